// Round 14
// baseline (406.094 us; speedup 1.0000x reference)
//
#include <hip/hip_runtime.h>

// TransformerWithLocalAttention: B=8, S=4096, D=512, BLOCK=64, window=3 blocks, FF=2048
// Round 14: multi-rep persistent GEMM blocks. R13 post-mortem: fixed cost
// F~37600cy per BLOCK (prologue+epilogue+drain+write burst), marginal tile
// cost ~2350cy (near MFMA floor) -> rounds are the waste. Now every GEMM is
// exactly 256 blocks (grid 128x2, 1/CU); each block loops R n-reps at fixed
// m0 (QKV R=3, FFN1 R=4, FFN2 R=1) re-running the proven R9/R12 2.5-buffer
// K-loop per rep. A-slice L2-reused across reps. Everything else = R12.

typedef __bf16 bf16;
typedef __bf16 bf16x8 __attribute__((ext_vector_type(8)));
typedef float  f32x4  __attribute__((ext_vector_type(4)));

#define DEV __device__ __forceinline__

#define BAR()  do { asm volatile("" ::: "memory"); __builtin_amdgcn_s_barrier(); asm volatile("" ::: "memory"); } while (0)
#define WAITV(n) asm volatile("s_waitcnt vmcnt(" #n ")" ::: "memory")
#define WAITV0() asm volatile("s_waitcnt vmcnt(0)" ::: "memory")

DEV void gload_lds16(const void* g, void* lds) {
  __builtin_amdgcn_global_load_lds(
      (const __attribute__((address_space(1))) void*)g,
      (__attribute__((address_space(3))) void*)lds, 16, 0, 0);
}

// ---------------- elementwise cast x -> bf16 ----------------
__global__ __launch_bounds__(256) void cast_to_bf16(const float* __restrict__ in,
                                                    bf16* __restrict__ out, int n8) {
  int i = blockIdx.x * 256 + threadIdx.x;
  if (i >= n8) return;
  float4 a0 = ((const float4*)in)[i * 2];
  float4 a1 = ((const float4*)in)[i * 2 + 1];
  bf16x8 o;
  o[0] = (bf16)a0.x; o[1] = (bf16)a0.y; o[2] = (bf16)a0.z; o[3] = (bf16)a0.w;
  o[4] = (bf16)a1.x; o[5] = (bf16)a1.y; o[6] = (bf16)a1.z; o[7] = (bf16)a1.w;
  ((bf16x8*)out)[i] = o;
}

// ---------------- merged weight prep: 5 transposes + bias concat ------------
DEV void tc_body(const float* __restrict__ W, bf16* __restrict__ Wt,
                 int K, int N, int n0, int k0, bf16 (*tile)[66]) {
  const int t = threadIdx.x;
#pragma unroll
  for (int it = 0; it < 16; ++it) {
    int c = it * 256 + t;
    int kr = c >> 6, nc = c & 63;
    tile[nc][kr] = (bf16)W[(size_t)(k0 + kr) * N + n0 + nc];
  }
  __syncthreads();
#pragma unroll
  for (int it = 0; it < 2; ++it) {
    int c = it * 256 + t;
    int nr = c >> 3, kg = (c & 7) * 8;
    bf16x8 v;
#pragma unroll
    for (int e = 0; e < 8; ++e) v[e] = tile[nr][kg + e];
    *(bf16x8*)(Wt + (size_t)(n0 + nr) * K + k0 + kg) = v;
  }
}

__global__ __launch_bounds__(256) void prep_weights(
    const float* __restrict__ Wq, const float* __restrict__ Wk,
    const float* __restrict__ Wv, const float* __restrict__ W1,
    const float* __restrict__ W2, const float* __restrict__ bq,
    const float* __restrict__ bk, const float* __restrict__ bv,
    bf16* __restrict__ WqkvT, bf16* __restrict__ W1T, bf16* __restrict__ W2T,
    float* __restrict__ bqkv) {
  __shared__ bf16 tile[64][66];
  const int bid = blockIdx.x;
  if (bid < 192) {
    const float* W = bid < 64 ? Wq : (bid < 128 ? Wk : Wv);
    bf16* Wt = WqkvT + (size_t)(bid >> 6) * 262144;
    const int t = bid & 63;
    tc_body(W, Wt, 512, 512, (t & 7) * 64, (t >> 3) * 64, tile);
  } else if (bid < 448) {
    const int t = bid - 192;
    tc_body(W1, W1T, 512, 2048, (t & 31) * 64, (t >> 5) * 64, tile);
  } else if (bid < 704) {
    const int t = bid - 448;
    tc_body(W2, W2T, 2048, 512, (t & 7) * 64, (t >> 3) * 64, tile);
  } else {
    for (int i = threadIdx.x; i < 512; i += 256) {
      bqkv[i] = bq[i];
      bqkv[512 + i] = bk[i];
      bqkv[1024 + i] = bv[i];
    }
  }
}

// ---------------- 256x256 GEMM multi-rep: 2.5-buffer, counted vmcnt ---------
// 512 thr = 8 waves (2M x 4N), wave tile 128x64. LDS 160KiB: A t%3, B t&1.
// Swizzle: LDS slot p of row r holds global chunk p^(r&7) (0 conflicts, R7).
// Grid 128x2 = 256 blocks (1/CU). Block does R reps at fixed m0, n0 varies:
// n0 = (nn*R + rep)*256. Per rep: zero acc, prologue, R9 K-loop, epilogue.
// XCD m-slice remap: xcd=bid&7 owns m-tiles [xcd*16,+16).
// VT: when vt!=null and n0>=1024, C tile written TRANSPOSED into vt[b][d][s].
// Requires M==32768, K%64==0, NT>=3, gridDim.x==128, gridDim.y==2.
template <int RELU, int F32OUT, int VT>
__global__ __launch_bounds__(512, 1)
void gemm256(const bf16* __restrict__ A, const bf16* __restrict__ Bt,
             const float* __restrict__ bias, void* __restrict__ Cout,
             bf16* __restrict__ vt, int M, int N, int K, int R) {
  __shared__ char LB[163840];  // 160 KiB
  const int tid = threadIdx.x;
  const int w = tid >> 6, l = tid & 63;
  const int lr = l & 15, lg = l >> 4;
  const int wm = w >> 2, wn = w & 3;

  const int bid = blockIdx.y * gridDim.x + blockIdx.x;
  const int NX = gridDim.y;  // 2
  const int xcd = bid & 7;
  const int idx = bid >> 3;
  const int mi = idx / NX;
  const int nn = idx - mi * NX;
  const int m0 = (xcd * 16 + mi) * 256;

  const int NT = K >> 6;

  int srow[4], scol[4];
#pragma unroll
  for (int j = 0; j < 4; ++j) {
    const int s = tid + 512 * j;
    srow[j] = s >> 3;
    scol[j] = (((s & 7) ^ ((s >> 3) & 7)) << 3);
  }

  const int swz0 = ((lg ^ (lr & 7)) << 4);
  const int swz1 = (((4 | lg) ^ (lr & 7)) << 4);

  int n0 = 0;

  auto stageA = [&](int t) {
    char* d = LB + (t % 3) * 32768 + tid * 16;
#pragma unroll
    for (int j = 0; j < 4; ++j)
      gload_lds16(A + (size_t)(m0 + srow[j]) * K + t * 64 + scol[j], d + j * 8192);
  };
  auto stageB = [&](int t) {
    char* d = LB + 98304 + (t & 1) * 32768 + tid * 16;
#pragma unroll
    for (int j = 0; j < 4; ++j)
      gload_lds16(Bt + (size_t)(n0 + srow[j]) * K + t * 64 + scol[j], d + j * 8192);
  };

  for (int rep = 0; rep < R; ++rep) {
    n0 = (nn * R + rep) * 256;

    f32x4 acc[8][4];
#pragma unroll
    for (int i = 0; i < 8; ++i)
#pragma unroll
      for (int j = 0; j < 4; ++j) acc[i][j] = f32x4{0.f, 0.f, 0.f, 0.f};

    // prologue (rep>0: WAITV counts leftover epilogue stores -> conservative)
    stageA(0); stageB(0); stageA(1);
    WAITV(4);
    BAR();

    for (int t = 0; t < NT; ++t) {
      if (t + 1 < NT) stageB(t + 1);
      if (t + 2 < NT) stageA(t + 2);
      const char* pA = LB + (t % 3) * 32768 + (wm << 14) + (lr << 7);
      const char* pB = LB + 98304 + (t & 1) * 32768 + (wn << 13) + (lr << 7);
      bf16x8 bv_[4][2];
#pragma unroll
      for (int n = 0; n < 4; ++n) {
        bv_[n][0] = *(const bf16x8*)(pB + n * 2048 + swz0);
        bv_[n][1] = *(const bf16x8*)(pB + n * 2048 + swz1);
      }
#pragma unroll
      for (int i = 0; i < 8; ++i) {
        bf16x8 a0 = *(const bf16x8*)(pA + i * 2048 + swz0);
        bf16x8 a1 = *(const bf16x8*)(pA + i * 2048 + swz1);
#pragma unroll
        for (int n = 0; n < 4; ++n) {
          acc[i][n] = __builtin_amdgcn_mfma_f32_16x16x32_bf16(a0, bv_[n][0], acc[i][n], 0, 0, 0);
          acc[i][n] = __builtin_amdgcn_mfma_f32_16x16x32_bf16(a1, bv_[n][1], acc[i][n], 0, 0, 0);
        }
      }
      if (t + 2 < NT) { WAITV(4); }
      else { WAITV0(); }
      BAR();
    }

    // ---- per-rep epilogue ----
    if (!F32OUT) {
      const bool is_v = VT && (n0 >= 1024);
      bf16* cl = (bf16*)LB;  // [128][264] padded, in A-buf region
      bf16* Cb = (bf16*)Cout;
#pragma unroll
      for (int half = 0; half < 2; ++half) {
        if (wm == half) {
#pragma unroll
          for (int n = 0; n < 4; ++n) {
            const int col = (wn << 6) + (n << 4) + lr;
            const float bv = bias[n0 + col];
#pragma unroll
            for (int m = 0; m < 8; ++m)
#pragma unroll
              for (int rg = 0; rg < 4; ++rg) {
                const int row = (m << 4) + (lg << 2) + rg;
                float v = acc[m][n][rg] + bv;
                if (RELU) v = fmaxf(v, 0.f);
                cl[row * 264 + col] = (bf16)v;
              }
        }
        }
        __syncthreads();
        if (!is_v) {
#pragma unroll
          for (int it = 0; it < 8; ++it) {
            const int idx2 = it * 512 + tid;
            const int r = idx2 >> 5, ch = idx2 & 31;
            *(bf16x8*)(Cb + (size_t)(m0 + half * 128 + r) * N + n0 + (ch << 3)) =
                *(const bf16x8*)(cl + r * 264 + (ch << 3));
          }
        } else {
          const int b = m0 >> 12;
          const int s0 = (m0 & 4095) + half * 128;
          const int d0 = n0 - 1024;
          const int d = tid >> 1, sc = (tid & 1) << 6;
          bf16* dst = vt + ((size_t)b * 512 + d0 + d) * 4096 + s0 + sc;
#pragma unroll
          for (int c8 = 0; c8 < 8; ++c8) {
            bf16x8 v;
#pragma unroll
            for (int e = 0; e < 8; ++e) v[e] = cl[(sc + c8 * 8 + e) * 264 + d];
            *(bf16x8*)(dst + c8 * 8) = v;
          }
        }
        __syncthreads();
      }
    } else {
      float* Cf = (float*)Cout;
#pragma unroll
      for (int n = 0; n < 4; ++n) {
        const int col = n0 + (wn << 6) + (n << 4) + lr;
        const float bv = bias[col];
#pragma unroll
        for (int m = 0; m < 8; ++m)
#pragma unroll
          for (int rg = 0; rg < 4; ++rg) {
            const int row = m0 + (wm << 7) + (m << 4) + (lg << 2) + rg;
            float v = acc[m][n][rg] + bv;
            if (RELU) v = fmaxf(v, 0.f);
            Cf[(size_t)row * N + col] = v;
          }
      }
      __syncthreads();
    }
  }
}

// ---------------- local attention (R5/R9 structure, unchanged) --------------
__global__ __launch_bounds__(512, 4)
void attn_local(const bf16* __restrict__ qkv, const bf16* __restrict__ vt,
                bf16* __restrict__ aout) {
  __shared__ bf16 P[4][16][200];
  __shared__ float xmx[4][2][16];
  __shared__ float xsm[4][2][16];
  const int qb = blockIdx.x, b = blockIdx.y;
  const int t = threadIdx.x, w = t >> 6, l = t & 63;
  const int rg = w & 3, h = w >> 2;
  const int lr = l & 15, lg = l >> 4;

  bool val[6];
#pragma unroll
  for (int n = 0; n < 6; ++n) {
    int gn = 6 * h + n;
    val[n] = ((unsigned)(qb - 1 + (gn >> 2)) < 64u);
  }

  const size_t qrow = (size_t)b * 4096 + qb * 64 + rg * 16;
  const bf16* qp = qkv + (qrow + lr) * 1536 + lg * 8;
  const bf16* kbase = qkv + ((long)b * 4096 + (long)(qb - 1) * 64) * 1536 + 512;

  f32x4 S[6];
#pragma unroll
  for (int n = 0; n < 6; ++n) S[n] = f32x4{0.f, 0.f, 0.f, 0.f};

  for (int kk = 0; kk < 16; ++kk) {
    bf16x8 aq = *(const bf16x8*)(qp + kk * 32);
#pragma unroll
    for (int n = 0; n < 6; ++n) {
      if (!val[n]) continue;
      const int gn = 6 * h + n;
      bf16x8 bk = *(const bf16x8*)(kbase + (size_t)(gn * 16 + lr) * 1536 + kk * 32 + lg * 8);
      S[n] = __builtin_amdgcn_mfma_f32_16x16x32_bf16(aq, bk, S[n], 0, 0, 0);
    }
  }

  const float scale = 0.044194173824159216f;  // 1/sqrt(512)
  float mx[4] = {-3e38f, -3e38f, -3e38f, -3e38f};
#pragma unroll
  for (int n = 0; n < 6; ++n) {
    if (!val[n]) continue;
#pragma unroll
    for (int i = 0; i < 4; ++i) mx[i] = fmaxf(mx[i], S[n][i]);
  }
#pragma unroll
  for (int i = 0; i < 4; ++i) {
    mx[i] = fmaxf(mx[i], __shfl_xor(mx[i], 1));
    mx[i] = fmaxf(mx[i], __shfl_xor(mx[i], 2));
    mx[i] = fmaxf(mx[i], __shfl_xor(mx[i], 4));
    mx[i] = fmaxf(mx[i], __shfl_xor(mx[i], 8));
  }
  if (lr == 0) {
#pragma unroll
    for (int i = 0; i < 4; ++i) xmx[rg][h][lg * 4 + i] = mx[i];
  }
  __syncthreads();
  float m4[4];
#pragma unroll
  for (int i = 0; i < 4; ++i) m4[i] = fmaxf(mx[i], xmx[rg][h ^ 1][lg * 4 + i]);

  float sm[4] = {0.f, 0.f, 0.f, 0.f};
#pragma unroll
  for (int n = 0; n < 6; ++n) {
    if (!val[n]) continue;
#pragma unroll
    for (int i = 0; i < 4; ++i) {
      float p = __expf((S[n][i] - m4[i]) * scale);
      S[n][i] = p;
      sm[i] += p;
    }
  }
#pragma unroll
  for (int i = 0; i < 4; ++i) {
    sm[i] += __shfl_xor(sm[i], 1);
    sm[i] += __shfl_xor(sm[i], 2);
    sm[i] += __shfl_xor(sm[i], 4);
    sm[i] += __shfl_xor(sm[i], 8);
  }
  if (lr == 0) {
#pragma unroll
    for (int i = 0; i < 4; ++i) xsm[rg][h][lg * 4 + i] = sm[i];
  }
  __syncthreads();
  float rinv[4];
#pragma unroll
  for (int i = 0; i < 4; ++i) rinv[i] = 1.f / (sm[i] + xsm[rg][h ^ 1][lg * 4 + i]);

#pragma unroll
  for (int n = 0; n < 6; ++n) {
    const int gn = 6 * h + n;
#pragma unroll
    for (int i = 0; i < 4; ++i)
      P[rg][lg * 4 + i][gn * 16 + lr] = val[n] ? (bf16)(S[n][i] * rinv[i]) : (bf16)0.f;
  }
  __syncthreads();

  f32x4 O[4][4];
#pragma unroll
  for (int rt = 0; rt < 4; ++rt)
#pragma unroll
    for (int dt = 0; dt < 4; ++dt) O[rt][dt] = f32x4{0.f, 0.f, 0.f, 0.f};

  const bf16* vtb = vt + ((long)b * 512 + w * 64) * 4096 + (long)(qb - 1) * 64;
#pragma unroll
  for (int ks = 0; ks < 6; ++ks) {
    if ((unsigned)(qb - 1 + (ks >> 1)) >= 64u) continue;
    bf16x8 vf[4];
#pragma unroll
    for (int dt = 0; dt < 4; ++dt)
      vf[dt] = *(const bf16x8*)(vtb + (size_t)(dt * 16 + lr) * 4096 + ks * 32 + lg * 8);
#pragma unroll
    for (int rt = 0; rt < 4; ++rt) {
      bf16x8 pa = *(const bf16x8*)&P[rt][lr][ks * 32 + lg * 8];
#pragma unroll
      for (int dt = 0; dt < 4; ++dt)
        O[rt][dt] = __builtin_amdgcn_mfma_f32_16x16x32_bf16(pa, vf[dt], O[rt][dt], 0, 0, 0);
    }
  }

  const size_t orow = (size_t)b * 4096 + qb * 64;
#pragma unroll
  for (int rt = 0; rt < 4; ++rt)
#pragma unroll
    for (int dt = 0; dt < 4; ++dt)
#pragma unroll
      for (int i = 0; i < 4; ++i)
        aout[(orow + rt * 16 + lg * 4 + i) * 512 + w * 64 + dt * 16 + lr] =
            (bf16)O[rt][dt][i];
}

// ---------------- LN1: out1 = LN(xb + a), a aliases out1 --------------------
__global__ __launch_bounds__(256) void ln_res1(const bf16* __restrict__ xb,
                                               const bf16* __restrict__ a,
                                               const float* __restrict__ g,
                                               const float* __restrict__ be,
                                               bf16* __restrict__ out) {
  const int t = threadIdx.x, w = t >> 6, l = t & 63;
  const size_t row = (size_t)blockIdx.x * 4 + w;
  bf16x8 xv = *(const bf16x8*)(xb + row * 512 + l * 8);
  bf16x8 av = *(const bf16x8*)(a + row * 512 + l * 8);
  float s[8];
#pragma unroll
  for (int i = 0; i < 8; ++i) s[i] = (float)xv[i] + (float)av[i];
  float sum = 0.f;
#pragma unroll
  for (int i = 0; i < 8; ++i) sum += s[i];
#pragma unroll
  for (int m = 1; m <= 32; m <<= 1) sum += __shfl_xor(sum, m);
  const float mean = sum * (1.f / 512.f);
  float vs = 0.f;
#pragma unroll
  for (int i = 0; i < 8; ++i) { float d = s[i] - mean; vs += d * d; }
#pragma unroll
  for (int m = 1; m <= 32; m <<= 1) vs += __shfl_xor(vs, m);
  const float r = rsqrtf(vs * (1.f / 512.f) + 1e-6f);
  float4 g0 = ((const float4*)(g + l * 8))[0], g1 = ((const float4*)(g + l * 8))[1];
  float4 b0 = ((const float4*)(be + l * 8))[0], b1 = ((const float4*)(be + l * 8))[1];
  bf16x8 o;
  o[0] = (bf16)(g0.x * (s[0] - mean) * r + b0.x);
  o[1] = (bf16)(g0.y * (s[1] - mean) * r + b0.y);
  o[2] = (bf16)(g0.z * (s[2] - mean) * r + b0.z);
  o[3] = (bf16)(g0.w * (s[3] - mean) * r + b0.w);
  o[4] = (bf16)(g1.x * (s[4] - mean) * r + b1.x);
  o[5] = (bf16)(g1.y * (s[5] - mean) * r + b1.y);
  o[6] = (bf16)(g1.z * (s[6] - mean) * r + b1.z);
  o[7] = (bf16)(g1.w * (s[7] - mean) * r + b1.w);
  *(bf16x8*)(out + row * 512 + l * 8) = o;
}

// ---------------- LN2: out_f32 = LN(out1 + y2), both bf16 -------------------
__global__ __launch_bounds__(256) void ln_res2b(const bf16* __restrict__ o1,
                                                const bf16* __restrict__ y2,
                                                const float* __restrict__ g,
                                                const float* __restrict__ be,
                                                float* __restrict__ out) {
  const int t = threadIdx.x, w = t >> 6, l = t & 63;
  const size_t row = (size_t)blockIdx.x * 4 + w;
  bf16x8 ov = *(const bf16x8*)(o1 + row * 512 + l * 8);
  bf16x8 yv = *(const bf16x8*)(y2 + row * 512 + l * 8);
  float s[8];
#pragma unroll
  for (int i = 0; i < 8; ++i) s[i] = (float)ov[i] + (float)yv[i];
  float sum = 0.f;
#pragma unroll
  for (int i = 0; i < 8; ++i) sum += s[i];
#pragma unroll
  for (int m = 1; m <= 32; m <<= 1) sum += __shfl_xor(sum, m);
  const float mean = sum * (1.f / 512.f);
  float vs = 0.f;
#pragma unroll
  for (int i = 0; i < 8; ++i) { float d = s[i] - mean; vs += d * d; }
#pragma unroll
  for (int m = 1; m <= 32; m <<= 1) vs += __shfl_xor(vs, m);
  const float r = rsqrtf(vs * (1.f / 512.f) + 1e-6f);
  float4 g0 = ((const float4*)(g + l * 8))[0], g1 = ((const float4*)(g + l * 8))[1];
  float4 b0 = ((const float4*)(be + l * 8))[0], b1 = ((const float4*)(be + l * 8))[1];
  float4 r0, r1;
  r0.x = g0.x * (s[0] - mean) * r + b0.x;
  r0.y = g0.y * (s[1] - mean) * r + b0.y;
  r0.z = g0.z * (s[2] - mean) * r + b0.z;
  r0.w = g0.w * (s[3] - mean) * r + b0.w;
  r1.x = g1.x * (s[4] - mean) * r + b1.x;
  r1.y = g1.y * (s[5] - mean) * r + b1.y;
  r1.z = g1.z * (s[6] - mean) * r + b1.z;
  r1.w = g1.w * (s[7] - mean) * r + b1.w;
  float* yp = out + row * 512 + l * 8;
  ((float4*)yp)[0] = r0;
  ((float4*)yp)[1] = r1;
}

extern "C" void kernel_launch(void* const* d_in, const int* in_sizes, int n_in,
                              void* d_out, int out_size, void* d_ws, size_t ws_size,
                              hipStream_t stream) {
  const float* x   = (const float*)d_in[0];
  const float* Wq  = (const float*)d_in[1];
  const float* bq  = (const float*)d_in[2];
  const float* Wk  = (const float*)d_in[3];
  const float* bk  = (const float*)d_in[4];
  const float* Wv  = (const float*)d_in[5];
  const float* bv  = (const float*)d_in[6];
  const float* W1  = (const float*)d_in[7];
  const float* b1  = (const float*)d_in[8];
  const float* W2  = (const float*)d_in[9];
  const float* b2  = (const float*)d_in[10];
  const float* g1  = (const float*)d_in[11];
  const float* be1 = (const float*)d_in[12];
  const float* g2  = (const float*)d_in[13];
  const float* be2 = (const float*)d_in[14];
  float* out = (float*)d_out;

  char* ws = (char*)d_ws;
  bf16*  WqkvT = (bf16*)(ws + 0);          // [1536][512]      1,572,864
  bf16*  W1T   = (bf16*)(ws + 1572864);    // [2048][512]      2,097,152
  bf16*  W2T   = (bf16*)(ws + 3670016);    // [512][2048]      2,097,152
  float* bqkv  = (float*)(ws + 5767168);   // [1536]           6,144
  bf16*  xb    = (bf16*)(ws + 6291456);    // [32768][512]     33,554,432
  bf16*  out1  = (bf16*)(ws + 39845888);   // [32768][512]     33,554,432
  bf16*  qkv   = (bf16*)(ws + 73400320);   // [32768][1536]    100,663,296
  bf16*  vtb   = (bf16*)(ws + 174063616);  // [8][512][4096]   33,554,432  -> end 207,618,048
  bf16*  a_    = out1;  // attn output lands in out1 region (LN1 elementwise in-place)
  bf16*  h     = qkv;   // h [32768][2048] reuses qkv+vtb (both dead by FFN1)
  bf16*  y2    = xb;    // FFN2 bf16 output reuses xb (dead after ln_res1)

  cast_to_bf16<<<8192, 256, 0, stream>>>(x, xb, 2097152);
  prep_weights<<<705, 256, 0, stream>>>(Wq, Wk, Wv, W1, W2, bq, bk, bv,
                                        WqkvT, W1T, W2T, bqkv);

  gemm256<0, 0, 1><<<dim3(128, 2), 512, 0, stream>>>(xb, WqkvT, bqkv, qkv, vtb,
                                                     32768, 1536, 512, 3);
  attn_local<<<dim3(64, 8), 512, 0, stream>>>(qkv, vtb, a_);
  ln_res1<<<8192, 256, 0, stream>>>(xb, a_, g1, be1, out1);
  gemm256<1, 0, 0><<<dim3(128, 2), 512, 0, stream>>>(out1, W1T, b1, h, nullptr,
                                                     32768, 2048, 512, 4);
  gemm256<0, 0, 0><<<dim3(128, 2), 512, 0, stream>>>(h, W2T, b2, y2, nullptr,
                                                     32768, 512, 2048, 1);
  ln_res2b<<<8192, 256, 0, stream>>>(out1, y2, g2, be2, out);
}

// Round 15
// 363.439 us; speedup vs baseline: 1.1174x; 1.1174x over previous
//
#include <hip/hip_runtime.h>

// TransformerWithLocalAttention: B=8, S=4096, D=512, BLOCK=64, window=3 blocks, FF=2048
// Round 15: GEMM core = R12 verbatim (best: 366.9us; R9/R11/R13/R14 schedule
// variants all null/negative -> plateaued, stop GEMM work). New: LN1 fused
// into attn_local. The attn block owns all 512 dims of its 64 rows, so LN is
// block-local: s = O + xb in-register (overwrites acc, no extra VGPR), 16
// row-partials/lane (sum+sumsq), shfl-reduce over lr, 4KB LDS cross-wave
// reduce, normalize, write out1 directly. Kills ln_res1 launch + a_ roundtrip
// (-66MB HBM). Everything else = R12.

typedef __bf16 bf16;
typedef __bf16 bf16x8 __attribute__((ext_vector_type(8)));
typedef float  f32x4  __attribute__((ext_vector_type(4)));

#define DEV __device__ __forceinline__

#define BAR()  do { asm volatile("" ::: "memory"); __builtin_amdgcn_s_barrier(); asm volatile("" ::: "memory"); } while (0)
#define WAITV(n) asm volatile("s_waitcnt vmcnt(" #n ")" ::: "memory")
#define WAITV0() asm volatile("s_waitcnt vmcnt(0)" ::: "memory")

DEV void gload_lds16(const void* g, void* lds) {
  __builtin_amdgcn_global_load_lds(
      (const __attribute__((address_space(1))) void*)g,
      (__attribute__((address_space(3))) void*)lds, 16, 0, 0);
}

// ---------------- elementwise cast x -> bf16 ----------------
__global__ __launch_bounds__(256) void cast_to_bf16(const float* __restrict__ in,
                                                    bf16* __restrict__ out, int n8) {
  int i = blockIdx.x * 256 + threadIdx.x;
  if (i >= n8) return;
  float4 a0 = ((const float4*)in)[i * 2];
  float4 a1 = ((const float4*)in)[i * 2 + 1];
  bf16x8 o;
  o[0] = (bf16)a0.x; o[1] = (bf16)a0.y; o[2] = (bf16)a0.z; o[3] = (bf16)a0.w;
  o[4] = (bf16)a1.x; o[5] = (bf16)a1.y; o[6] = (bf16)a1.z; o[7] = (bf16)a1.w;
  ((bf16x8*)out)[i] = o;
}

// ---------------- merged weight prep: 5 transposes + bias concat ------------
DEV void tc_body(const float* __restrict__ W, bf16* __restrict__ Wt,
                 int K, int N, int n0, int k0, bf16 (*tile)[66]) {
  const int t = threadIdx.x;
#pragma unroll
  for (int it = 0; it < 16; ++it) {
    int c = it * 256 + t;
    int kr = c >> 6, nc = c & 63;
    tile[nc][kr] = (bf16)W[(size_t)(k0 + kr) * N + n0 + nc];
  }
  __syncthreads();
#pragma unroll
  for (int it = 0; it < 2; ++it) {
    int c = it * 256 + t;
    int nr = c >> 3, kg = (c & 7) * 8;
    bf16x8 v;
#pragma unroll
    for (int e = 0; e < 8; ++e) v[e] = tile[nr][kg + e];
    *(bf16x8*)(Wt + (size_t)(n0 + nr) * K + k0 + kg) = v;
  }
}

__global__ __launch_bounds__(256) void prep_weights(
    const float* __restrict__ Wq, const float* __restrict__ Wk,
    const float* __restrict__ Wv, const float* __restrict__ W1,
    const float* __restrict__ W2, const float* __restrict__ bq,
    const float* __restrict__ bk, const float* __restrict__ bv,
    bf16* __restrict__ WqkvT, bf16* __restrict__ W1T, bf16* __restrict__ W2T,
    float* __restrict__ bqkv) {
  __shared__ bf16 tile[64][66];
  const int bid = blockIdx.x;
  if (bid < 192) {
    const float* W = bid < 64 ? Wq : (bid < 128 ? Wk : Wv);
    bf16* Wt = WqkvT + (size_t)(bid >> 6) * 262144;
    const int t = bid & 63;
    tc_body(W, Wt, 512, 512, (t & 7) * 64, (t >> 3) * 64, tile);
  } else if (bid < 448) {
    const int t = bid - 192;
    tc_body(W1, W1T, 512, 2048, (t & 31) * 64, (t >> 5) * 64, tile);
  } else if (bid < 704) {
    const int t = bid - 448;
    tc_body(W2, W2T, 2048, 512, (t & 7) * 64, (t >> 3) * 64, tile);
  } else {
    for (int i = threadIdx.x; i < 512; i += 256) {
      bqkv[i] = bq[i];
      bqkv[512 + i] = bk[i];
      bqkv[1024 + i] = bv[i];
    }
  }
}

// ---------------- 256x256 GEMM (R12): BK=64, 2.5-buffer, counted vmcnt ------
// 512 thr = 8 waves (2M x 4N), wave tile 128x64. LDS 160KiB: A t%3, B t&1.
// Swizzle: LDS slot p of row r holds global chunk p^(r&7) (0 conflicts, R7).
// XCD m-slice remap. VT: when vt!=null and n0>=1024, the epilogue writes the
// C tile TRANSPOSED into vt[b][d][s] (V never lands in qkv).
// Requires M==32768, N%256==0, K%64==0, NT>=3, gridDim.x==128.
template <int RELU, int F32OUT, int VT>
__global__ __launch_bounds__(512, 1)
void gemm256(const bf16* __restrict__ A, const bf16* __restrict__ Bt,
             const float* __restrict__ bias, void* __restrict__ Cout,
             bf16* __restrict__ vt, int M, int N, int K) {
  __shared__ char LB[163840];  // 160 KiB
  const int tid = threadIdx.x;
  const int w = tid >> 6, l = tid & 63;
  const int lr = l & 15, lg = l >> 4;
  const int wm = w >> 2, wn = w & 3;

  const int bid = blockIdx.y * gridDim.x + blockIdx.x;
  const int NX = gridDim.y;
  const int xcd = bid & 7;
  const int idx = bid >> 3;
  const int mi = idx / NX;
  const int nn = idx - mi * NX;
  const int m0 = (xcd * 16 + mi) * 256;
  const int n0 = nn * 256;

  const int NT = K >> 6;

  int srow[4], scol[4];
#pragma unroll
  for (int j = 0; j < 4; ++j) {
    const int s = tid + 512 * j;
    srow[j] = s >> 3;
    scol[j] = (((s & 7) ^ ((s >> 3) & 7)) << 3);
  }

  const int swz0 = ((lg ^ (lr & 7)) << 4);
  const int swz1 = (((4 | lg) ^ (lr & 7)) << 4);

  f32x4 acc[8][4];
#pragma unroll
  for (int i = 0; i < 8; ++i)
#pragma unroll
    for (int j = 0; j < 4; ++j) acc[i][j] = f32x4{0.f, 0.f, 0.f, 0.f};

  auto stageA = [&](int t) {
    char* d = LB + (t % 3) * 32768 + tid * 16;
#pragma unroll
    for (int j = 0; j < 4; ++j)
      gload_lds16(A + (size_t)(m0 + srow[j]) * K + t * 64 + scol[j], d + j * 8192);
  };
  auto stageB = [&](int t) {
    char* d = LB + 98304 + (t & 1) * 32768 + tid * 16;
#pragma unroll
    for (int j = 0; j < 4; ++j)
      gload_lds16(Bt + (size_t)(n0 + srow[j]) * K + t * 64 + scol[j], d + j * 8192);
  };

  stageA(0); stageB(0); stageA(1);
  WAITV(4);
  BAR();

  for (int t = 0; t < NT; ++t) {
    if (t + 1 < NT) stageB(t + 1);
    if (t + 2 < NT) stageA(t + 2);
    const char* pA = LB + (t % 3) * 32768 + (wm << 14) + (lr << 7);
    const char* pB = LB + 98304 + (t & 1) * 32768 + (wn << 13) + (lr << 7);
    bf16x8 bv_[4][2];
#pragma unroll
    for (int n = 0; n < 4; ++n) {
      bv_[n][0] = *(const bf16x8*)(pB + n * 2048 + swz0);
      bv_[n][1] = *(const bf16x8*)(pB + n * 2048 + swz1);
    }
#pragma unroll
    for (int i = 0; i < 8; ++i) {
      bf16x8 a0 = *(const bf16x8*)(pA + i * 2048 + swz0);
      bf16x8 a1 = *(const bf16x8*)(pA + i * 2048 + swz1);
#pragma unroll
      for (int n = 0; n < 4; ++n) {
        acc[i][n] = __builtin_amdgcn_mfma_f32_16x16x32_bf16(a0, bv_[n][0], acc[i][n], 0, 0, 0);
        acc[i][n] = __builtin_amdgcn_mfma_f32_16x16x32_bf16(a1, bv_[n][1], acc[i][n], 0, 0, 0);
      }
    }
    if (t + 2 < NT) { WAITV(4); }
    else { WAITV0(); }
    BAR();
  }

  // ---- epilogue ----
  if (!F32OUT) {
    const bool is_v = VT && (n0 >= 1024);
    bf16* cl = (bf16*)LB;  // [128][264] padded
    bf16* Cb = (bf16*)Cout;
#pragma unroll
    for (int half = 0; half < 2; ++half) {
      if (wm == half) {
#pragma unroll
        for (int n = 0; n < 4; ++n) {
          const int col = (wn << 6) + (n << 4) + lr;
          const float bv = bias[n0 + col];
#pragma unroll
          for (int m = 0; m < 8; ++m)
#pragma unroll
            for (int rg = 0; rg < 4; ++rg) {
              const int row = (m << 4) + (lg << 2) + rg;
              float v = acc[m][n][rg] + bv;
              if (RELU) v = fmaxf(v, 0.f);
              cl[row * 264 + col] = (bf16)v;
            }
        }
      }
      __syncthreads();
      if (!is_v) {
#pragma unroll
        for (int it = 0; it < 8; ++it) {
          const int idx2 = it * 512 + tid;
          const int r = idx2 >> 5, ch = idx2 & 31;
          *(bf16x8*)(Cb + (size_t)(m0 + half * 128 + r) * N + n0 + (ch << 3)) =
              *(const bf16x8*)(cl + r * 264 + (ch << 3));
        }
      } else {
        const int b = m0 >> 12;
        const int s0 = (m0 & 4095) + half * 128;
        const int d0 = n0 - 1024;
        const int d = tid >> 1, sc = (tid & 1) << 6;
        bf16* dst = vt + ((size_t)b * 512 + d0 + d) * 4096 + s0 + sc;
#pragma unroll
        for (int c8 = 0; c8 < 8; ++c8) {
          bf16x8 v;
#pragma unroll
          for (int e = 0; e < 8; ++e) v[e] = cl[(sc + c8 * 8 + e) * 264 + d];
          *(bf16x8*)(dst + c8 * 8) = v;
        }
      }
      __syncthreads();
    }
  } else {
    float* Cf = (float*)Cout;
#pragma unroll
    for (int n = 0; n < 4; ++n) {
      const int col = n0 + (wn << 6) + (n << 4) + lr;
      const float bv = bias[col];
#pragma unroll
      for (int m = 0; m < 8; ++m)
#pragma unroll
        for (int rg = 0; rg < 4; ++rg) {
          const int row = m0 + (wm << 7) + (m << 4) + (lg << 2) + rg;
          float v = acc[m][n][rg] + bv;
          if (RELU) v = fmaxf(v, 0.f);
          Cf[(size_t)row * N + col] = v;
        }
    }
  }
}

// ---------------- local attention + fused residual/LN1 ----------------------
// grid (64, 8), 512 threads = 8 waves. Wave (rg = w&3, h = w>>2):
//   QK^T: rows rg*16..+16, score cols [96h,96h+96); softmax via LDS h-pair;
//   rinv folded into P. PV: wave w -> all 64 rows x dims [w*64,+64).
// Fused LN1: s = O + xb (overwrites acc, f32); 16 row-partials/lane; shfl
// reduce over lr; rsum/rsq[64][8] LDS cross-wave reduce; normalize; write out1.
__global__ __launch_bounds__(512, 4)
void attn_local(const bf16* __restrict__ qkv, const bf16* __restrict__ vt,
                const bf16* __restrict__ xb, const float* __restrict__ g1,
                const float* __restrict__ be1, bf16* __restrict__ out1) {
  __shared__ bf16 P[4][16][200];
  __shared__ float xmx[4][2][16];
  __shared__ float xsm[4][2][16];
  __shared__ float rsum[64][8];
  __shared__ float rsq[64][8];
  const int qb = blockIdx.x, b = blockIdx.y;
  const int t = threadIdx.x, w = t >> 6, l = t & 63;
  const int rg = w & 3, h = w >> 2;
  const int lr = l & 15, lg = l >> 4;

  bool val[6];
#pragma unroll
  for (int n = 0; n < 6; ++n) {
    int gn = 6 * h + n;
    val[n] = ((unsigned)(qb - 1 + (gn >> 2)) < 64u);
  }

  const size_t qrow = (size_t)b * 4096 + qb * 64 + rg * 16;
  const bf16* qp = qkv + (qrow + lr) * 1536 + lg * 8;
  const bf16* kbase = qkv + ((long)b * 4096 + (long)(qb - 1) * 64) * 1536 + 512;

  f32x4 S[6];
#pragma unroll
  for (int n = 0; n < 6; ++n) S[n] = f32x4{0.f, 0.f, 0.f, 0.f};

  for (int kk = 0; kk < 16; ++kk) {
    bf16x8 aq = *(const bf16x8*)(qp + kk * 32);
#pragma unroll
    for (int n = 0; n < 6; ++n) {
      if (!val[n]) continue;
      const int gn = 6 * h + n;
      bf16x8 bk = *(const bf16x8*)(kbase + (size_t)(gn * 16 + lr) * 1536 + kk * 32 + lg * 8);
      S[n] = __builtin_amdgcn_mfma_f32_16x16x32_bf16(aq, bk, S[n], 0, 0, 0);
    }
  }

  const float scale = 0.044194173824159216f;  // 1/sqrt(512)
  float mx[4] = {-3e38f, -3e38f, -3e38f, -3e38f};
#pragma unroll
  for (int n = 0; n < 6; ++n) {
    if (!val[n]) continue;
#pragma unroll
    for (int i = 0; i < 4; ++i) mx[i] = fmaxf(mx[i], S[n][i]);
  }
#pragma unroll
  for (int i = 0; i < 4; ++i) {
    mx[i] = fmaxf(mx[i], __shfl_xor(mx[i], 1));
    mx[i] = fmaxf(mx[i], __shfl_xor(mx[i], 2));
    mx[i] = fmaxf(mx[i], __shfl_xor(mx[i], 4));
    mx[i] = fmaxf(mx[i], __shfl_xor(mx[i], 8));
  }
  if (lr == 0) {
#pragma unroll
    for (int i = 0; i < 4; ++i) xmx[rg][h][lg * 4 + i] = mx[i];
  }
  __syncthreads();
  float m4[4];
#pragma unroll
  for (int i = 0; i < 4; ++i) m4[i] = fmaxf(mx[i], xmx[rg][h ^ 1][lg * 4 + i]);

  float sm[4] = {0.f, 0.f, 0.f, 0.f};
#pragma unroll
  for (int n = 0; n < 6; ++n) {
    if (!val[n]) continue;
#pragma unroll
    for (int i = 0; i < 4; ++i) {
      float p = __expf((S[n][i] - m4[i]) * scale);
      S[n][i] = p;
      sm[i] += p;
    }
  }
#pragma unroll
  for (int i = 0; i < 4; ++i) {
    sm[i] += __shfl_xor(sm[i], 1);
    sm[i] += __shfl_xor(sm[i], 2);
    sm[i] += __shfl_xor(sm[i], 4);
    sm[i] += __shfl_xor(sm[i], 8);
  }
  if (lr == 0) {
#pragma unroll
    for (int i = 0; i < 4; ++i) xsm[rg][h][lg * 4 + i] = sm[i];
  }
  __syncthreads();
  float rinv[4];
#pragma unroll
  for (int i = 0; i < 4; ++i) rinv[i] = 1.f / (sm[i] + xsm[rg][h ^ 1][lg * 4 + i]);

#pragma unroll
  for (int n = 0; n < 6; ++n) {
    const int gn = 6 * h + n;
#pragma unroll
    for (int i = 0; i < 4; ++i)
      P[rg][lg * 4 + i][gn * 16 + lr] = val[n] ? (bf16)(S[n][i] * rinv[i]) : (bf16)0.f;
  }
  __syncthreads();

  f32x4 O[4][4];
#pragma unroll
  for (int rt = 0; rt < 4; ++rt)
#pragma unroll
    for (int dt = 0; dt < 4; ++dt) O[rt][dt] = f32x4{0.f, 0.f, 0.f, 0.f};

  const bf16* vtb = vt + ((long)b * 512 + w * 64) * 4096 + (long)(qb - 1) * 64;
#pragma unroll
  for (int ks = 0; ks < 6; ++ks) {
    if ((unsigned)(qb - 1 + (ks >> 1)) >= 64u) continue;
    bf16x8 vf[4];
#pragma unroll
    for (int dt = 0; dt < 4; ++dt)
      vf[dt] = *(const bf16x8*)(vtb + (size_t)(dt * 16 + lr) * 4096 + ks * 32 + lg * 8);
#pragma unroll
    for (int rt = 0; rt < 4; ++rt) {
      bf16x8 pa = *(const bf16x8*)&P[rt][lr][ks * 32 + lg * 8];
#pragma unroll
      for (int dt = 0; dt < 4; ++dt)
        O[rt][dt] = __builtin_amdgcn_mfma_f32_16x16x32_bf16(pa, vf[dt], O[rt][dt], 0, 0, 0);
    }
  }

  // ---- fused residual + LN1 ----
  const size_t orow = (size_t)b * 4096 + qb * 64;
  const bf16* xrow = xb + orow * 512;
  float psum[16], psq[16];
#pragma unroll
  for (int p = 0; p < 16; ++p) { psum[p] = 0.f; psq[p] = 0.f; }
#pragma unroll
  for (int rt = 0; rt < 4; ++rt)
#pragma unroll
    for (int i = 0; i < 4; ++i) {
      const int row = rt * 16 + lg * 4 + i;
#pragma unroll
      for (int dt = 0; dt < 4; ++dt) {
        const int col = w * 64 + dt * 16 + lr;
        float s = O[rt][dt][i] + (float)xrow[(size_t)row * 512 + col];
        O[rt][dt][i] = s;
        psum[rt * 4 + i] += s;
        psq[rt * 4 + i] += s * s;
      }
    }
#pragma unroll
  for (int p = 0; p < 16; ++p) {
#pragma unroll
    for (int m = 1; m <= 8; m <<= 1) {
      psum[p] += __shfl_xor(psum[p], m);
      psq[p]  += __shfl_xor(psq[p], m);
    }
  }
  if (lr == 0) {
#pragma unroll
    for (int rt = 0; rt < 4; ++rt)
#pragma unroll
      for (int i = 0; i < 4; ++i) {
        rsum[rt * 16 + lg * 4 + i][w] = psum[rt * 4 + i];
        rsq[rt * 16 + lg * 4 + i][w]  = psq[rt * 4 + i];
      }
  }
  __syncthreads();

  float gv[4], bev[4];
#pragma unroll
  for (int dt = 0; dt < 4; ++dt) {
    gv[dt]  = g1[w * 64 + dt * 16 + lr];
    bev[dt] = be1[w * 64 + dt * 16 + lr];
  }
#pragma unroll
  for (int rt = 0; rt < 4; ++rt)
#pragma unroll
    for (int i = 0; i < 4; ++i) {
      const int row = rt * 16 + lg * 4 + i;
      float4 s0 = ((const float4*)rsum[row])[0], s1 = ((const float4*)rsum[row])[1];
      float4 q0 = ((const float4*)rsq[row])[0],  q1 = ((const float4*)rsq[row])[1];
      const float tot = s0.x + s0.y + s0.z + s0.w + s1.x + s1.y + s1.z + s1.w;
      const float tq  = q0.x + q0.y + q0.z + q0.w + q1.x + q1.y + q1.z + q1.w;
      const float mean = tot * (1.f / 512.f);
      const float var  = tq * (1.f / 512.f) - mean * mean;
      const float rn = rsqrtf(var + 1e-6f);
#pragma unroll
      for (int dt = 0; dt < 4; ++dt) {
        const int col = w * 64 + dt * 16 + lr;
        const float o = gv[dt] * (O[rt][dt][i] - mean) * rn + bev[dt];
        out1[(orow + row) * 512 + col] = (bf16)o;
      }
    }
}

// ---------------- LN2: out_f32 = LN(out1 + y2), both bf16 -------------------
__global__ __launch_bounds__(256) void ln_res2b(const bf16* __restrict__ o1,
                                                const bf16* __restrict__ y2,
                                                const float* __restrict__ g,
                                                const float* __restrict__ be,
                                                float* __restrict__ out) {
  const int t = threadIdx.x, w = t >> 6, l = t & 63;
  const size_t row = (size_t)blockIdx.x * 4 + w;
  bf16x8 ov = *(const bf16x8*)(o1 + row * 512 + l * 8);
  bf16x8 yv = *(const bf16x8*)(y2 + row * 512 + l * 8);
  float s[8];
#pragma unroll
  for (int i = 0; i < 8; ++i) s[i] = (float)ov[i] + (float)yv[i];
  float sum = 0.f;
#pragma unroll
  for (int i = 0; i < 8; ++i) sum += s[i];
#pragma unroll
  for (int m = 1; m <= 32; m <<= 1) sum += __shfl_xor(sum, m);
  const float mean = sum * (1.f / 512.f);
  float vs = 0.f;
#pragma unroll
  for (int i = 0; i < 8; ++i) { float d = s[i] - mean; vs += d * d; }
#pragma unroll
  for (int m = 1; m <= 32; m <<= 1) vs += __shfl_xor(vs, m);
  const float r = rsqrtf(vs * (1.f / 512.f) + 1e-6f);
  float4 g0 = ((const float4*)(g + l * 8))[0], g1 = ((const float4*)(g + l * 8))[1];
  float4 b0 = ((const float4*)(be + l * 8))[0], b1 = ((const float4*)(be + l * 8))[1];
  float4 r0, r1;
  r0.x = g0.x * (s[0] - mean) * r + b0.x;
  r0.y = g0.y * (s[1] - mean) * r + b0.y;
  r0.z = g0.z * (s[2] - mean) * r + b0.z;
  r0.w = g0.w * (s[3] - mean) * r + b0.w;
  r1.x = g1.x * (s[4] - mean) * r + b1.x;
  r1.y = g1.y * (s[5] - mean) * r + b1.y;
  r1.z = g1.z * (s[6] - mean) * r + b1.z;
  r1.w = g1.w * (s[7] - mean) * r + b1.w;
  float* yp = out + row * 512 + l * 8;
  ((float4*)yp)[0] = r0;
  ((float4*)yp)[1] = r1;
}

extern "C" void kernel_launch(void* const* d_in, const int* in_sizes, int n_in,
                              void* d_out, int out_size, void* d_ws, size_t ws_size,
                              hipStream_t stream) {
  const float* x   = (const float*)d_in[0];
  const float* Wq  = (const float*)d_in[1];
  const float* bq  = (const float*)d_in[2];
  const float* Wk  = (const float*)d_in[3];
  const float* bk  = (const float*)d_in[4];
  const float* Wv  = (const float*)d_in[5];
  const float* bv  = (const float*)d_in[6];
  const float* W1  = (const float*)d_in[7];
  const float* b1  = (const float*)d_in[8];
  const float* W2  = (const float*)d_in[9];
  const float* b2  = (const float*)d_in[10];
  const float* g1  = (const float*)d_in[11];
  const float* be1 = (const float*)d_in[12];
  const float* g2  = (const float*)d_in[13];
  const float* be2 = (const float*)d_in[14];
  float* out = (float*)d_out;

  char* ws = (char*)d_ws;
  bf16*  WqkvT = (bf16*)(ws + 0);          // [1536][512]      1,572,864
  bf16*  W1T   = (bf16*)(ws + 1572864);    // [2048][512]      2,097,152
  bf16*  W2T   = (bf16*)(ws + 3670016);    // [512][2048]      2,097,152
  float* bqkv  = (float*)(ws + 5767168);   // [1536]           6,144
  bf16*  xb    = (bf16*)(ws + 6291456);    // [32768][512]     33,554,432
  bf16*  out1  = (bf16*)(ws + 39845888);   // [32768][512]     33,554,432
  bf16*  qkv   = (bf16*)(ws + 73400320);   // [32768][1536]    100,663,296
  bf16*  vtb   = (bf16*)(ws + 174063616);  // [8][512][4096]   33,554,432  -> end 207,618,048
  bf16*  h     = qkv;   // h [32768][2048] reuses qkv+vtb (both dead by FFN1)
  bf16*  y2    = xb;    // FFN2 bf16 output reuses xb (dead after attn's LN1)

  cast_to_bf16<<<8192, 256, 0, stream>>>(x, xb, 2097152);
  prep_weights<<<705, 256, 0, stream>>>(Wq, Wk, Wv, W1, W2, bq, bk, bv,
                                        WqkvT, W1T, W2T, bqkv);

  gemm256<0, 0, 1><<<dim3(128, 6), 512, 0, stream>>>(xb, WqkvT, bqkv, qkv, vtb,
                                                     32768, 1536, 512);
  attn_local<<<dim3(64, 8), 512, 0, stream>>>(qkv, vtb, xb, g1, be1, out1);
  gemm256<1, 0, 0><<<dim3(128, 8), 512, 0, stream>>>(out1, W1T, b1, h, nullptr,
                                                     32768, 2048, 512);
  gemm256<0, 0, 0><<<dim3(128, 2), 512, 0, stream>>>(h, W2T, b2, y2, nullptr,
                                                     32768, 512, 2048);
  ln_res2b<<<8192, 256, 0, stream>>>(out1, y2, g2, be2, out);
}